// Round 2
// baseline (10710.470 us; speedup 1.0000x reference)
//
#include <hip/hip_runtime.h>
#include <cmath>

#define BATCH 2048
#define TSTEPS 16384

// ---- rate functions in float64 (tracks the harness's f64 NumPy golden) ----
__device__ __forceinline__ double alpha_m_d(double V) {
    double x = V + 40.0;
    double den = 1.0 - exp(-x / 10.0) + 1e-8;
    return (fabs(x) < 1e-6) ? 1.0 : (0.1 * x) / den;
}
__device__ __forceinline__ double beta_m_d(double V) {
    return 4.0 * exp(-(V + 65.0) / 18.0);
}
__device__ __forceinline__ double alpha_h_d(double V) {
    return 0.07 * exp(-(V + 65.0) / 20.0);
}
__device__ __forceinline__ double beta_h_d(double V) {
    return 1.0 / (1.0 + exp(-(V + 35.0) / 10.0));
}
__device__ __forceinline__ double alpha_n_d(double V) {
    double x = V + 55.0;
    double den = 1.0 - exp(-x / 10.0) + 1e-8;
    return (fabs(x) < 1e-6) ? 0.1 : (0.01 * x) / den;
}
__device__ __forceinline__ double beta_n_d(double V) {
    return 0.125 * exp(-(V + 65.0) / 80.0);
}

__global__ __launch_bounds__(64, 1)
void hh_scan_kernel(const float* __restrict__ I,
                    const float* __restrict__ rgNa,
                    const float* __restrict__ rgK,
                    const float* __restrict__ rgL,
                    float* __restrict__ out)
{
    const int b = blockIdx.x * 64 + threadIdx.x;
    if (b >= BATCH) return;

    // softplus(x) = max(x,0) + log1p(exp(-|x|))  in f64
    double gNa, gK, gL;
    {
        double x = (double)rgNa[0]; gNa = fmax(x, 0.0) + log1p(exp(-fabs(x)));
        x = (double)rgK[0];         gK  = fmax(x, 0.0) + log1p(exp(-fabs(x)));
        x = (double)rgL[0];         gL  = fmax(x, 0.0) + log1p(exp(-fabs(x)));
    }

    const float* __restrict__ Ip = I + (size_t)b * TSTEPS;
    float*       __restrict__ Op = out + (size_t)b * TSTEPS;

    double V = -65.0;
    double m, h, n;
    {
        double am0 = alpha_m_d(V), bm0 = beta_m_d(V);
        double ah0 = alpha_h_d(V), bh0 = beta_h_d(V);
        double an0 = alpha_n_d(V), bn0 = beta_n_d(V);
        m = am0 / (am0 + bm0);
        h = ah0 / (ah0 + bh0);
        n = an0 / (an0 + bn0);
    }

    const double DT = 0.02;

    auto step = [&](float I_t) {
        double am = alpha_m_d(V), bm = beta_m_d(V);
        double ah = alpha_h_d(V), bh = beta_h_d(V);
        double an = alpha_n_d(V), bn = beta_n_d(V);
        double INa = gNa * m * m * m * h * (V - 50.0);
        double nn = n * n;
        double IK = gK * (nn * nn) * (V + 77.0);
        double IL = gL * (V + 54.387);
        double Iion = INa + IK + IL;
        m = m + DT * (am * (1.0 - m) - bm * m);
        h = h + DT * (ah * (1.0 - h) - bh * h);
        n = n + DT * (an * (1.0 - n) - bn * n);
        V = V + DT * ((double)I_t - Iion);
    };

    const int NCH = TSTEPS / 8;  // 2048 chunks of 8 timesteps

    float4 ia = reinterpret_cast<const float4*>(Ip)[0];
    float4 ib = reinterpret_cast<const float4*>(Ip)[1];

    for (int c = 0; c < NCH - 1; ++c) {
        const float cur[8] = {ia.x, ia.y, ia.z, ia.w, ib.x, ib.y, ib.z, ib.w};
        // prefetch next chunk — 8 f64 steps of compute easily hide HBM latency
        ia = reinterpret_cast<const float4*>(Ip)[2 * (c + 1)];
        ib = reinterpret_cast<const float4*>(Ip)[2 * (c + 1) + 1];

        float ob[8];
        #pragma unroll
        for (int j = 0; j < 8; ++j) {
            ob[j] = (float)V;   // out[p] = V after p steps (out[0] = V0)
            step(cur[j]);
        }
        reinterpret_cast<float4*>(Op)[2 * c]     = make_float4(ob[0], ob[1], ob[2], ob[3]);
        reinterpret_cast<float4*>(Op)[2 * c + 1] = make_float4(ob[4], ob[5], ob[6], ob[7]);
    }

    // last chunk: positions T-8 .. T-1; only 7 steps (I[T-1] unused)
    {
        const int c = NCH - 1;
        const float cur[8] = {ia.x, ia.y, ia.z, ia.w, ib.x, ib.y, ib.z, ib.w};
        float ob[8];
        #pragma unroll
        for (int j = 0; j < 8; ++j) {
            ob[j] = (float)V;
            if (j < 7) step(cur[j]);
        }
        reinterpret_cast<float4*>(Op)[2 * c]     = make_float4(ob[0], ob[1], ob[2], ob[3]);
        reinterpret_cast<float4*>(Op)[2 * c + 1] = make_float4(ob[4], ob[5], ob[6], ob[7]);
    }
}

extern "C" void kernel_launch(void* const* d_in, const int* in_sizes, int n_in,
                              void* d_out, int out_size, void* d_ws, size_t ws_size,
                              hipStream_t stream) {
    const float* I    = (const float*)d_in[0];
    const float* rgNa = (const float*)d_in[1];
    const float* rgK  = (const float*)d_in[2];
    const float* rgL  = (const float*)d_in[3];
    float* out = (float*)d_out;

    hh_scan_kernel<<<dim3(BATCH / 64), dim3(64), 0, stream>>>(I, rgNa, rgK, rgL, out);
}

// Round 3
// 3813.514 us; speedup vs baseline: 2.8086x; 2.8086x over previous
//
#include <hip/hip_runtime.h>
#include <cmath>

#define BATCH 2048
#define TSTEPS 16384

// Per-slot rate-function constants.  Uniform form per lane:
//   e   = exp(A*V + B)
//   num = (C + D*V) * (useE ? e : 1)
//   den = P + Q*e
//   r   = num / den;  if |V - fixV| < 1e-6 -> fixR
// slots: 0=alpha_m 1=beta_m 2=alpha_h 3=beta_h 4=alpha_n 5=beta_n 6,7=dummy
__device__ __constant__ double CA[8]    = {-0.1, -1.0/18.0, -0.05, -0.1, -0.1, -0.0125, 0.0, 0.0};
__device__ __constant__ double CBc[8]   = {-4.0, -65.0/18.0, -3.25, -3.5, -5.5, -0.8125, 0.0, 0.0};
__device__ __constant__ double CC[8]    = {4.0, 4.0, 0.07, 1.0, 0.55, 0.125, 0.0, 0.0};
__device__ __constant__ double CD[8]    = {0.1, 0.0, 0.0, 0.0, 0.01, 0.0, 0.0, 0.0};
__device__ __constant__ double CP[8]    = {1.0 + 1e-8, 1.0, 1.0, 1.0, 1.0 + 1e-8, 1.0, 1.0, 1.0};
__device__ __constant__ double CQ[8]    = {-1.0, 0.0, 0.0, 1.0, -1.0, 0.0, 0.0, 0.0};
__device__ __constant__ int    CUSEE[8] = {0, 1, 1, 0, 0, 1, 0, 0};
__device__ __constant__ double CFV[8]   = {-40.0, 1e300, 1e300, 1e300, -55.0, 1e300, 1e300, 1e300};
__device__ __constant__ double CFR[8]   = {1.0, 0.0, 0.0, 0.0, 0.1, 0.0, 0.0, 0.0};

// fast f64 exp: Cody-Waite + degree-10 Taylor.  rel err ~2e-13 over |arg|<~20.
__device__ __forceinline__ double fast_exp(double x) {
    const double L2E    = 1.4426950408889634074;
    const double LN2_HI = 6.93147180369123816490e-01;  // 20 trailing zero bits
    const double LN2_LO = 1.90821492927058770002e-10;
    double nd = rint(x * L2E);
    double t  = fma(-nd, LN2_HI, x);
    t = fma(-nd, LN2_LO, t);
    double p = 2.755731922398589e-7;              // 1/10!
    p = fma(p, t, 2.755731922398589e-6);          // 1/9!
    p = fma(p, t, 2.4801587301587302e-5);         // 1/8!
    p = fma(p, t, 1.984126984126984e-4);          // 1/7!
    p = fma(p, t, 1.3888888888888889e-3);         // 1/6!
    p = fma(p, t, 8.333333333333333e-3);          // 1/5!
    p = fma(p, t, 4.1666666666666664e-2);         // 1/4!
    p = fma(p, t, 1.6666666666666666e-1);         // 1/3!
    p = fma(p, t, 0.5);
    p = fma(p, t, 1.0);
    p = fma(p, t, 1.0);                            // note: last two give 1 + t + ...
    int i = (int)nd;
    double sc = __longlong_as_double((long long)(1023 + i) << 52);
    return p * sc;
}

__device__ __forceinline__ double shfl_f64(double v, int srcLane) {
    int lo = __shfl(__double2loint(v), srcLane, 64);
    int hi = __shfl(__double2hiint(v), srcLane, 64);
    return __hiloint2double(hi, lo);
}
__device__ __forceinline__ double shflxor_f64(double v, int mask) {
    int lo = __shfl_xor(__double2loint(v), mask, 64);
    int hi = __shfl_xor(__double2hiint(v), mask, 64);
    return __hiloint2double(hi, lo);
}

__global__ __launch_bounds__(64, 1)
void hh8_kernel(const float* __restrict__ I,
                const float* __restrict__ rgNa,
                const float* __restrict__ rgK,
                const float* __restrict__ rgL,
                float* __restrict__ out)
{
    const int lane = threadIdx.x;        // block == 1 wave of 64
    const int slot = lane & 7;           // rate slot within neuron group
    const int base = lane & ~7;          // first lane of this neuron's group
    const int nb   = blockIdx.x * 8 + (lane >> 3);   // neuron index

    // per-lane rate constants
    const double A  = CA[slot],  Bc = CBc[slot];
    const double C  = CC[slot],  D  = CD[slot];
    const double P  = CP[slot],  Q  = CQ[slot];
    const bool useE = CUSEE[slot] != 0;
    const double fixV = CFV[slot], fixR = CFR[slot];

    // softplus(x) = max(x,0) + log1p(exp(-|x|))
    double gNa, gK, gL;
    {
        double x = (double)rgNa[0]; gNa = fmax(x, 0.0) + log1p(exp(-fabs(x)));
        x = (double)rgK[0];         gK  = fmax(x, 0.0) + log1p(exp(-fabs(x)));
        x = (double)rgL[0];         gL  = fmax(x, 0.0) + log1p(exp(-fabs(x)));
    }

    const double DT = 0.02;
    double V = -65.0, m, h, n;

    // ---- initial gate values: x0 = a/(a+b) ----
    {
        double y = fma(A, V, Bc);
        double e = fast_exp(y);
        double num = fma(D, V, C);
        num = useE ? num * e : num;
        double den = fma(Q, e, P);
        double r = num / den;
        r = (fabs(V - fixV) < 1e-6) ? fixR : r;
        double Bv = shflxor_f64(r, 1);
        double x0 = r / (r + Bv);
        m = shfl_f64(x0, base + 0);
        h = shfl_f64(x0, base + 2);
        n = shfl_f64(x0, base + 4);
    }

    const float* __restrict__ Ip = I   + (size_t)nb * TSTEPS + slot;
    float*       __restrict__ Op = out + (size_t)nb * TSTEPS + slot;

    // one fully-uniform Euler step (all 64 lanes execute the same instructions)
    auto step = [&](float It) {
        double y = fma(A, V, Bc);
        double e = fast_exp(y);
        double num = fma(D, V, C);
        num = useE ? num * e : num;
        double den = fma(Q, e, P);
        double r = num / den;
        r = (fabs(V - fixV) < 1e-6) ? fixR : r;
        double Bv = shflxor_f64(r, 1);          // partner rate (beta for even slots)
        // own gate value for this lane's update slot
        double g0 = (slot < 2) ? m : (slot < 4) ? h : n;
        double gn = fma(DT, fma(-Bv, g0, r * (1.0 - g0)), g0);
        // V update, uniform on all lanes (state is replicated)
        double m3  = m * m * m;
        double INa = gNa * m3 * h * (V - 50.0);
        double nn2 = n * n;
        double IK  = gK * (nn2 * nn2) * (V + 77.0);
        double IL  = gL * (V + 54.387);
        double Iion = INa + IK + IL;
        double Vn  = fma(DT, (double)It - Iion, V);
        // broadcast new gates from their owner lanes
        m = shfl_f64(gn, base + 0);
        h = shfl_f64(gn, base + 2);
        n = shfl_f64(gn, base + 4);
        V = Vn;
    };

    const int NCH = TSTEPS / 8;
    float icur = Ip[0];                    // lane holds I[nb][c*8 + slot]

    for (int c = 0; c < NCH - 1; ++c) {
        float inext = Ip[(c + 1) * 8];     // prefetch next chunk
        float vs = 0.0f;
        #pragma unroll
        for (int j = 0; j < 8; ++j) {
            vs = (slot == j) ? (float)V : vs;          // out[p] = V after p steps
            float It = __shfl(icur, base + j, 64);     // I[nb][c*8+j] to whole group
            step(It);
        }
        Op[c * 8] = vs;
        icur = inext;
    }
    // epilogue chunk: save 8 positions, step only first 7 (I[T-1] unused)
    {
        float vs = 0.0f;
        #pragma unroll
        for (int j = 0; j < 8; ++j) {
            vs = (slot == j) ? (float)V : vs;
            if (j < 7) {
                float It = __shfl(icur, base + j, 64);
                step(It);
            }
        }
        Op[(NCH - 1) * 8] = vs;
    }
}

extern "C" void kernel_launch(void* const* d_in, const int* in_sizes, int n_in,
                              void* d_out, int out_size, void* d_ws, size_t ws_size,
                              hipStream_t stream) {
    const float* I    = (const float*)d_in[0];
    const float* rgNa = (const float*)d_in[1];
    const float* rgK  = (const float*)d_in[2];
    const float* rgL  = (const float*)d_in[3];
    float* out = (float*)d_out;

    hh8_kernel<<<dim3(BATCH / 8), dim3(64), 0, stream>>>(I, rgNa, rgK, rgL, out);
}

// Round 4
// 3268.866 us; speedup vs baseline: 3.2765x; 1.1666x over previous
//
#include <hip/hip_runtime.h>
#include <cmath>

#define BATCH 2048
#define TSTEPS 16384

// Uniform per-slot rate form:  e = exp(A*V + B);  r = (C + D*V)*e / (P + Q*e)
// (alpha_m, alpha_n, beta_h multiplied through by e^{+x/10} so ALL slots share it)
// slots: 0=alpha_m 1=beta_m 2=alpha_h 3=beta_h 4=alpha_n 5=beta_n 6,7=spare
__device__ __constant__ double CA[8]  = {0.1, -1.0/18.0, -0.05, 0.1, 0.1, -0.0125, 0.0, 0.0};
__device__ __constant__ double CB[8]  = {4.0, -65.0/18.0, -3.25, 3.5, 5.5, -0.8125, 0.0, 0.0};
__device__ __constant__ double CC[8]  = {4.0, 4.0, 0.07, 1.0, 0.55, 0.125, 1.0, 1.0};
__device__ __constant__ double CD[8]  = {0.1, 0.0, 0.0, 0.0, 0.01, 0.0, 0.0, 0.0};
__device__ __constant__ double CP[8]  = {-1.0, 1.0, 1.0, 1.0, -1.0, 1.0, 1.0, 1.0};
__device__ __constant__ double CQ[8]  = {1.0 + 1e-8, 0.0, 0.0, 1.0, 1.0 + 1e-8, 0.0, 0.0, 0.0};
__device__ __constant__ double CFV[8] = {-40.0, 1e300, 1e300, 1e300, -55.0, 1e300, 1e300, 1e300};
__device__ __constant__ double CFR[8] = {1.0, 0.0, 0.0, 0.0, 0.1, 0.0, 0.0, 0.0};

// fast f64 exp: Cody-Waite + even/odd-split degree-9 Taylor.  rel err ~7e-12.
__device__ __forceinline__ double fast_exp(double x) {
    const double L2E    = 1.4426950408889634074;
    const double LN2_HI = 6.93147180369123816490e-01;
    const double LN2_LO = 1.90821492927058770002e-10;
    double nd = rint(x * L2E);
    double t  = fma(-nd, LN2_HI, x);
    t = fma(-nd, LN2_LO, t);
    double u = t * t;
    // even part: 1 + u/2 + u^2/24 + u^3/720 + u^4/40320
    double q = fma(u, 2.48015873015873016e-5, 1.38888888888888889e-3);
    q = fma(u, q, 4.16666666666666667e-2);
    q = fma(u, q, 0.5);
    q = fma(u, q, 1.0);
    // odd part /t: 1 + u/6 + u^2/120 + u^3/5040 + u^4/362880
    double s = fma(u, 2.75573192239858907e-6, 1.98412698412698413e-4);
    s = fma(u, s, 8.33333333333333333e-3);
    s = fma(u, s, 1.66666666666666667e-1);
    s = fma(u, s, 1.0);
    double p = fma(t, s, q);
    int i = (int)nd;
    double sc = __longlong_as_double((long long)(1023 + i) << 52);
    return p * sc;
}

__device__ __forceinline__ double shfl_f64(double v, int srcLane) {
    int lo = __shfl(__double2loint(v), srcLane, 64);
    int hi = __shfl(__double2hiint(v), srcLane, 64);
    return __hiloint2double(hi, lo);
}
__device__ __forceinline__ double shflxor_f64(double v, int mask) {
    int lo = __shfl_xor(__double2loint(v), mask, 64);
    int hi = __shfl_xor(__double2hiint(v), mask, 64);
    return __hiloint2double(hi, lo);
}

__global__ __launch_bounds__(64, 1)
void hh8p_kernel(const float* __restrict__ I,
                 const float* __restrict__ rgNa,
                 const float* __restrict__ rgK,
                 const float* __restrict__ rgL,
                 float* __restrict__ out)
{
    const int lane = threadIdx.x;       // block == 1 wave
    const int slot = lane & 7;
    const int base = lane & ~7;
    const int nb   = blockIdx.x * 8 + (lane >> 3);

    const double A = CA[slot], Bc = CB[slot];
    const double C = CC[slot], D  = CD[slot];
    const double P = CP[slot], Q  = CQ[slot];
    const double fixV = CFV[slot], fixR = CFR[slot];

    // softplus(x) = max(x,0) + log1p(exp(-|x|))
    double gNa, gK, gL;
    {
        double x = (double)rgNa[0]; gNa = fmax(x, 0.0) + log1p(exp(-fabs(x)));
        x = (double)rgK[0];         gK  = fmax(x, 0.0) + log1p(exp(-fabs(x)));
        x = (double)rgL[0];         gL  = fmax(x, 0.0) + log1p(exp(-fabs(x)));
    }

    const double DT = 0.02;

    auto rate = [&](double Vx) -> double {
        double e   = fast_exp(fma(A, Vx, Bc));
        double num = fma(D, Vx, C) * e;
        double den = fma(Q, e, P);
        double r0  = num / den;
        return (fabs(Vx - fixV) < 1e-6) ? fixR : r0;
    };

    double V = -65.0, m, h, n;
    double r = rate(V);                 // pipelined: rate for the CURRENT V
    {
        double rb = shflxor_f64(r, 1);
        double x0 = r / (r + rb);       // a/(a+b) on even lanes
        m = shfl_f64(x0, base + 0);
        h = shfl_f64(x0, base + 2);
        n = shfl_f64(x0, base + 4);
    }

    const float* __restrict__ Ip = I + (size_t)nb * TSTEPS;    // same ptr across group
    float*       __restrict__ Op = out + (size_t)nb * TSTEPS + slot;

    // one Euler step, software-pipelined: r == rate(V) already in hand.
    // Order: issue xor early -> V-update (covers broadcast wait) ->
    //        next-step rate chain (covers xor wait) -> gate update -> broadcast.
    auto step = [&](float It) {
        double rb = shflxor_f64(r, 1);                     // partner rate, in flight
        double m3  = m * m * m;
        double nn2 = n * n;
        double Iion = gNa * m3 * h * (V - 50.0)
                    + gK * (nn2 * nn2) * (V + 77.0)
                    + gL * (V + 54.387);
        double Vn = fma(DT, (double)It - Iion, V);
        double rn = rate(Vn);                              // long chain, hides rb wait
        double g0 = (slot < 2) ? m : (slot < 4) ? h : n;
        double gn = fma(DT, fma(-rb, g0, r * (1.0 - g0)), g0);
        m = shfl_f64(gn, base + 0);
        h = shfl_f64(gn, base + 2);
        n = shfl_f64(gn, base + 4);
        V = Vn;
        r = rn;
    };

    const int NCH = TSTEPS / 8;
    float4 ia = reinterpret_cast<const float4*>(Ip)[0];
    float4 ib = reinterpret_cast<const float4*>(Ip)[1];

    for (int c = 0; c < NCH - 1; ++c) {
        const float cur[8] = {ia.x, ia.y, ia.z, ia.w, ib.x, ib.y, ib.z, ib.w};
        ia = reinterpret_cast<const float4*>(Ip)[2 * (c + 1)];
        ib = reinterpret_cast<const float4*>(Ip)[2 * (c + 1) + 1];
        float vs = 0.0f;
        #pragma unroll
        for (int j = 0; j < 8; ++j) {
            vs = (slot == j) ? (float)V : vs;   // out[p] = V after p steps
            step(cur[j]);
        }
        Op[c * 8] = vs;
    }
    // epilogue chunk: save 8 positions, step only the first 7 (I[T-1] unused)
    {
        const float cur[8] = {ia.x, ia.y, ia.z, ia.w, ib.x, ib.y, ib.z, ib.w};
        float vs = 0.0f;
        #pragma unroll
        for (int j = 0; j < 8; ++j) {
            vs = (slot == j) ? (float)V : vs;
            if (j < 7) step(cur[j]);
        }
        Op[(NCH - 1) * 8] = vs;
    }
}

extern "C" void kernel_launch(void* const* d_in, const int* in_sizes, int n_in,
                              void* d_out, int out_size, void* d_ws, size_t ws_size,
                              hipStream_t stream) {
    const float* I    = (const float*)d_in[0];
    const float* rgNa = (const float*)d_in[1];
    const float* rgK  = (const float*)d_in[2];
    const float* rgL  = (const float*)d_in[3];
    float* out = (float*)d_out;

    hh8p_kernel<<<dim3(BATCH / 8), dim3(64), 0, stream>>>(I, rgNa, rgK, rgL, out);
}

// Round 5
// 2436.331 us; speedup vs baseline: 4.3961x; 1.3417x over previous
//
#include <hip/hip_runtime.h>
#include <cmath>

#define BATCH 2048
#define TSTEPS 16384

#define L2E 1.4426950408889634074
#define DTC 0.02

// Uniform per-slot rate form (DT and log2e folded):
//   e = 2^(A2*V + B2);   r' = DT*rate = (Cd + Dd*V) * e / (P + Q*e)
// slots: 0=alpha_m 1=beta_m 2=alpha_h 3=beta_h 4=alpha_n 5=beta_n 6,7=spare
__device__ __constant__ double CA2[8] = {0.1*L2E, -(1.0/18.0)*L2E, -0.05*L2E, 0.1*L2E, 0.1*L2E, -0.0125*L2E, 0.0, 0.0};
__device__ __constant__ double CB2[8] = {4.0*L2E, -(65.0/18.0)*L2E, -3.25*L2E, 3.5*L2E, 5.5*L2E, -0.8125*L2E, 0.0, 0.0};
__device__ __constant__ double CCd[8] = {DTC*4.0, DTC*4.0, DTC*0.07, DTC*1.0, DTC*0.55, DTC*0.125, DTC, DTC};
__device__ __constant__ double CDd[8] = {DTC*0.1, 0.0, 0.0, 0.0, DTC*0.01, 0.0, 0.0, 0.0};
__device__ __constant__ double CP[8]  = {-1.0, 1.0, 1.0, 1.0, -1.0, 1.0, 1.0, 1.0};
__device__ __constant__ double CQ[8]  = {1.0+1e-8, 0.0, 0.0, 1.0, 1.0+1e-8, 0.0, 0.0, 0.0};
__device__ __constant__ double CFV[8] = {-40.0, 1e300, 1e300, 1e300, -55.0, 1e300, 1e300, 1e300};
__device__ __constant__ double CFR[8] = {DTC*1.0, 0.0, 0.0, 0.0, DTC*0.1, 0.0, 0.0, 0.0};

// exp2 in f64: magic-number reduction + deg-9 even/odd Taylor + exponent injection.
// rel err ~1e-11 for the |t|<=0.5 range.  ~15 VALU ops.
__device__ __forceinline__ double exp2d(double y) {
    const double C52 = 6755399441055744.0;      // 1.5 * 2^52
    double z  = y + C52;
    double nf = z - C52;                         // round-to-nearest(y)
    double t  = y - nf;                          // exact, in [-0.5, 0.5]
    int    i  = __double2loint(z);               // integer part, two's complement
    double u  = t * t;
    // exp2(t) = q(u) + t*s(u), coeffs = ln2^k / k!
    double q = fma(u, 1.3215486790144309e-6, 1.5403530393381610e-4);
    q = fma(u, q, 9.6181291076284772e-3);
    q = fma(u, q, 2.4022650695910071e-1);
    q = fma(u, q, 1.0);
    double s = fma(u, 1.0178086009239696e-7, 1.5252733804059840e-5);
    s = fma(u, s, 1.3333558146428443e-3);
    s = fma(u, s, 5.5504108664821580e-2);
    s = fma(u, s, 6.9314718055994531e-1);
    double p = fma(t, s, q);                     // in [0.70, 1.42]
    int hi = __double2hiint(p) + (i << 20);      // multiply by 2^i via exponent add
    return __hiloint2double(hi, __double2loint(p));
}

__device__ __forceinline__ double rcp64(double d) {
#if __has_builtin(__builtin_amdgcn_rcp)
    double x = __builtin_amdgcn_rcp(d);
#else
    double x; asm("v_rcp_f64 %0, %1" : "=v"(x) : "v"(d));
#endif
    // one Newton step: 2^-29 seed -> ~2^-52
    return fma(x, fma(-d, x, 1.0), x);
}

// index-free lane exchange within 8-lane groups via ds_swizzle (BitMode)
template<int PAT>
__device__ __forceinline__ double swz_f64(double v) {
    int lo = __builtin_amdgcn_ds_swizzle(__double2loint(v), PAT);
    int hi = __builtin_amdgcn_ds_swizzle(__double2hiint(v), PAT);
    return __hiloint2double(hi, lo);
}
#define SWZ_XOR1  0x041F            // lane ^ 1
#define SWZ_BC(k) (((k) << 5) | 0x18)   // broadcast lane (base|k) to 8-group

__global__ __launch_bounds__(64, 1)
void hh8q_kernel(const float* __restrict__ I,
                 const float* __restrict__ rgNa,
                 const float* __restrict__ rgK,
                 const float* __restrict__ rgL,
                 float* __restrict__ out)
{
    const int lane = threadIdx.x;               // block == 1 wave
    const int slot = lane & 7;
    const int nb   = blockIdx.x * 8 + (lane >> 3);

    const double A2 = CA2[slot], B2 = CB2[slot];
    const double Cd = CCd[slot], Dd = CDd[slot];
    const double P  = CP[slot],  Q  = CQ[slot];
    const double fixV = CFV[slot], fixR = CFR[slot];

    // softplus(x) = max(x,0) + log1p(exp(-|x|))
    double gNa, gK, gL;
    {
        double x = (double)rgNa[0]; gNa = fmax(x, 0.0) + log1p(exp(-fabs(x)));
        x = (double)rgK[0];         gK  = fmax(x, 0.0) + log1p(exp(-fabs(x)));
        x = (double)rgL[0];         gL  = fmax(x, 0.0) + log1p(exp(-fabs(x)));
    }
    // folded V-update constants: V' = V*S1 + (DT*I + S2)
    //   S1 = (1 - DT*gL) - a - b,  S2 = 50a - 77b - 54.387*DT*gL
    const double kNa = DTC * gNa;
    const double kK  = DTC * gK;
    const double K1  = 1.0 - DTC * gL;
    const double K2  = -54.387 * (DTC * gL);

    auto rate = [&](double Vx) -> double {
        double e   = exp2d(fma(A2, Vx, B2));
        double num = fma(Dd, Vx, Cd) * e;
        double den = fma(Q, e, P);
        double r0  = num * rcp64(den);
        return (fabs(Vx - fixV) < 1e-6) ? fixR : r0;
    };

    double V = -65.0;
    double r = rate(V);                 // pipelined: r == DT*rate(V_cur)
    double g, m, h, n;                  // g = own gate (valid on even lanes)
    {
        double rb = swz_f64<SWZ_XOR1>(r);
        g = r / (r + rb);               // alpha/(alpha+beta) on even lanes
        m = swz_f64<SWZ_BC(0)>(g);
        h = swz_f64<SWZ_BC(2)>(g);
        n = swz_f64<SWZ_BC(4)>(g);
    }

    const float* __restrict__ Ip = I + (size_t)nb * TSTEPS;
    float*       __restrict__ Op = out + (size_t)nb * TSTEPS + slot;

    // One Euler step.  Order chosen so: xor latency hides under V-update,
    // broadcast latency hides under the next-rate chain.
    auto step = [&](float It) {
        double rb = swz_f64<SWZ_XOR1>(r);           // partner rate, in flight
        // ---- V-update from OLD gates (broadcasts of prev step) ----
        double mm  = m * m,  mh = m * h;
        double m3h = mm * mh;
        double nn  = n * n;
        double n4  = nn * nn;
        double a   = kNa * m3h;
        double b   = kK * n4;
        double S1  = (K1 - a) - b;
        double S2  = fma(-77.0, b, fma(50.0, a, K2));
        double Vn  = fma(V, S1, fma(DTC, (double)It, S2));
        // ---- gate update on own lane (even lanes correct; odd lanes junk) ----
        double sr = r + rb;
        double gt = g + r;
        g = fma(-sr, g, gt);
        // ---- broadcast new gates (latency covered by rate chain below) ----
        m = swz_f64<SWZ_BC(0)>(g);
        h = swz_f64<SWZ_BC(2)>(g);
        n = swz_f64<SWZ_BC(4)>(g);
        // ---- next-step rate ----
        r = rate(Vn);
        V = Vn;
    };

    const int NCH = TSTEPS / 8;
    float4 ia = reinterpret_cast<const float4*>(Ip)[0];
    float4 ib = reinterpret_cast<const float4*>(Ip)[1];

    for (int c = 0; c < NCH - 1; ++c) {
        const float cur[8] = {ia.x, ia.y, ia.z, ia.w, ib.x, ib.y, ib.z, ib.w};
        ia = reinterpret_cast<const float4*>(Ip)[2 * (c + 1)];
        ib = reinterpret_cast<const float4*>(Ip)[2 * (c + 1) + 1];
        float vs = 0.0f;
        #pragma unroll
        for (int j = 0; j < 8; ++j) {
            vs = (slot == j) ? (float)V : vs;   // out[p] = V after p steps
            step(cur[j]);
        }
        Op[c * 8] = vs;
    }
    // epilogue chunk: save 8 positions, step only the first 7 (I[T-1] unused)
    {
        const float cur[8] = {ia.x, ia.y, ia.z, ia.w, ib.x, ib.y, ib.z, ib.w};
        float vs = 0.0f;
        #pragma unroll
        for (int j = 0; j < 8; ++j) {
            vs = (slot == j) ? (float)V : vs;
            if (j < 7) step(cur[j]);
        }
        Op[(NCH - 1) * 8] = vs;
    }
}

extern "C" void kernel_launch(void* const* d_in, const int* in_sizes, int n_in,
                              void* d_out, int out_size, void* d_ws, size_t ws_size,
                              hipStream_t stream) {
    const float* I    = (const float*)d_in[0];
    const float* rgNa = (const float*)d_in[1];
    const float* rgK  = (const float*)d_in[2];
    const float* rgL  = (const float*)d_in[3];
    float* out = (float*)d_out;

    hh8q_kernel<<<dim3(BATCH / 8), dim3(64), 0, stream>>>(I, rgNa, rgK, rgL, out);
}